// Round 1
// baseline (215.530 us; speedup 1.0000x reference)
//
#include <hip/hip_runtime.h>
#include <math.h>

// Group-limited MoE router, T=131072 tokens x E=256 experts.
// 8 lanes per token, one lane per expert-group (32 experts).
// Per lane: 32 biased scores in registers as 8 sorted chunks of 4;
// global top-8 = 8 rounds of (chunk-head argmax -> 8-lane butterfly argmax
// -> winner stream advance). All tie-breaks: lower index first (top_k stable).

__global__ __launch_bounds__(256) void router_topk_kernel(
    const float* __restrict__ logits,
    const float* __restrict__ bias,
    float* __restrict__ out_w,
    float* __restrict__ out_id,
    int T)
{
    const float NEGINF = -__builtin_inff();
    const int tid = threadIdx.x;
    const int s = tid & 7;                      // expert-group owned by this lane
    const int token = blockIdx.x * 32 + (tid >> 3);
    if (token >= T) return;

    const float* row = logits + (size_t)token * 256 + s * 32;
    const float* brw = bias + s * 32;

    float v[8][4];
    int   ix[8][4];

    // ---- load 32 logits, sigmoid, add bias ----
    #pragma unroll
    for (int c = 0; c < 8; ++c) {
        float4 l = ((const float4*)row)[c];
        float4 b = ((const float4*)brw)[c];
        v[c][0] = 1.0f / (1.0f + expf(-l.x)) + b.x;
        v[c][1] = 1.0f / (1.0f + expf(-l.y)) + b.y;
        v[c][2] = 1.0f / (1.0f + expf(-l.z)) + b.z;
        v[c][3] = 1.0f / (1.0f + expf(-l.w)) + b.w;
        ix[c][0] = s * 32 + c * 4 + 0;
        ix[c][1] = s * 32 + c * 4 + 1;
        ix[c][2] = s * 32 + c * 4 + 2;
        ix[c][3] = s * 32 + c * 4 + 3;
    }

    // ---- group score: sum of top-2 of my 32 biased values ----
    float t1 = NEGINF, t2 = NEGINF;
    #pragma unroll
    for (int c = 0; c < 8; ++c) {
        #pragma unroll
        for (int k = 0; k < 4; ++k) {
            float val = v[c][k];
            t2 = fmaxf(t2, fminf(t1, val));
            t1 = fmaxf(t1, val);
        }
    }
    float gs = t1 + t2;

    // ---- rank my group among the 8; keep top-4 (ties -> lower group id) ----
    int rank = 0;
    #pragma unroll
    for (int j = 0; j < 8; ++j) {
        float gsj = __shfl(gs, j, 8);
        rank += (gsj > gs || (gsj == gs && j < s)) ? 1 : 0;
    }
    const bool selected = rank < 4;

    #pragma unroll
    for (int c = 0; c < 8; ++c) {
        #pragma unroll
        for (int k = 0; k < 4; ++k)
            v[c][k] = selected ? v[c][k] : NEGINF;
    }

    // ---- sort each chunk of 4 descending (ties -> lower idx first) ----
    #pragma unroll
    for (int c = 0; c < 8; ++c) {
        #define CE(a,b) { \
            bool sw = (v[c][a] < v[c][b]) || (v[c][a] == v[c][b] && ix[c][a] > ix[c][b]); \
            float tv = sw ? v[c][b] : v[c][a]; \
            float uv = sw ? v[c][a] : v[c][b]; \
            int   ti = sw ? ix[c][b] : ix[c][a]; \
            int   ui = sw ? ix[c][a] : ix[c][b]; \
            v[c][a] = tv; v[c][b] = uv; ix[c][a] = ti; ix[c][b] = ui; }
        CE(0,1) CE(2,3) CE(0,2) CE(1,3) CE(1,2)
        #undef CE
    }

    // ---- 8 rounds: global argmax over 64 stream heads, advance winner ----
    float keepV = 0.0f; int keepI = 0;
    const int sbase8 = s << 3;
    #pragma unroll
    for (int r = 0; r < 8; ++r) {
        float bv = v[0][0]; int bi = ix[0][0];
        #pragma unroll
        for (int c = 1; c < 8; ++c) {
            bool t = (v[c][0] > bv) || (v[c][0] == bv && ix[c][0] < bi);
            bv = t ? v[c][0] : bv;
            bi = t ? ix[c][0] : bi;
        }
        #pragma unroll
        for (int m = 1; m < 8; m <<= 1) {
            float ov = __shfl_xor(bv, m, 8);
            int   oi = __shfl_xor(bi, m, 8);
            bool t = (ov > bv) || (ov == bv && oi < bi);
            bv = t ? ov : bv;
            bi = t ? oi : bi;
        }
        if (s == r) { keepV = bv; keepI = bi; }
        const int d = (bi >> 2) - sbase8;   // my chunk index if winner is mine
        #pragma unroll
        for (int c = 0; c < 8; ++c) {
            bool hit = (d == c);
            v[c][0]  = hit ? v[c][1]  : v[c][0];
            ix[c][0] = hit ? ix[c][1] : ix[c][0];
            v[c][1]  = hit ? v[c][2]  : v[c][1];
            ix[c][1] = hit ? ix[c][2] : ix[c][1];
            v[c][2]  = hit ? v[c][3]  : v[c][2];
            ix[c][2] = hit ? ix[c][3] : ix[c][2];
            v[c][3]  = hit ? NEGINF   : v[c][3];
        }
    }

    // ---- recover sigmoid score, renormalize, scale, store (coalesced) ----
    float w = keepV - bias[keepI];
    float sum = w;
    sum += __shfl_xor(sum, 1, 8);
    sum += __shfl_xor(sum, 2, 8);
    sum += __shfl_xor(sum, 4, 8);
    w = w / (sum + 1e-20f) * 2.5f;

    out_w[(size_t)token * 8 + s]  = w;
    out_id[(size_t)token * 8 + s] = (float)keepI;
}

extern "C" void kernel_launch(void* const* d_in, const int* in_sizes, int n_in,
                              void* d_out, int out_size, void* d_ws, size_t ws_size,
                              hipStream_t stream) {
    const float* logits = (const float*)d_in[0];
    const float* bias   = (const float*)d_in[1];
    const int E = in_sizes[1];          // 256
    const int T = in_sizes[0] / E;      // 131072
    float* out_w  = (float*)d_out;
    float* out_id = out_w + (size_t)T * 8;
    const int blocks = (T + 31) / 32;
    router_topk_kernel<<<blocks, 256, 0, stream>>>(logits, bias, out_w, out_id, T);
}

// Round 3
// 210.243 us; speedup vs baseline: 1.0251x; 1.0251x over previous
//
#include <hip/hip_runtime.h>
#include <math.h>

// Group-limited MoE router, T=131072 tokens x E=256 experts.
// 8 lanes per token, one lane per expert-group (32 experts).
// Round 3: exact sigmoid restored (bit-identical to Round 1 -> ids match np),
// keep ds_swizzle butterflies + trimmed tie-breaks, head-scan as depth-3 tree.

#define SWZF(x, mask) __int_as_float(__builtin_amdgcn_ds_swizzle(__float_as_int(x), (((mask) << 10) | 0x1F)))
#define SWZI(x, mask) __builtin_amdgcn_ds_swizzle((x), (((mask) << 10) | 0x1F))

__global__ __launch_bounds__(256) void router_topk_kernel(
    const float* __restrict__ logits,
    const float* __restrict__ bias,
    float* __restrict__ out_w,
    float* __restrict__ out_id,
    int T)
{
    const float NEGINF = -__builtin_inff();
    const int tid = threadIdx.x;
    const int s = tid & 7;                      // expert-group owned by this lane
    const int token = blockIdx.x * 32 + (tid >> 3);
    if (token >= T) return;

    const float* row = logits + (size_t)token * 256 + s * 32;
    const float* brw = bias + s * 32;

    float v[8][4];
    int   ix[8][4];

    // ---- load 32 logits, exact sigmoid (matches np ordering), add bias ----
    #pragma unroll
    for (int c = 0; c < 8; ++c) {
        float4 l = ((const float4*)row)[c];
        float4 b = ((const float4*)brw)[c];
        #pragma unroll
        for (int k = 0; k < 4; ++k) {
            float x = (&l.x)[k];
            v[c][k] = 1.0f / (1.0f + expf(-x)) + (&b.x)[k];
            ix[c][k] = s * 32 + c * 4 + k;
        }
    }

    // ---- group score: sum of top-2 of my 32 biased values ----
    float t1 = NEGINF, t2 = NEGINF;
    #pragma unroll
    for (int c = 0; c < 8; ++c) {
        #pragma unroll
        for (int k = 0; k < 4; ++k) {
            float val = v[c][k];
            t2 = fmaxf(t2, fminf(t1, val));
            t1 = fmaxf(t1, val);
        }
    }
    const float gs = t1 + t2;

    // ---- rank my group among the 8 via xor-swizzles; keep top-4 ----
    // partner j = s^m; on tie lower group id wins: j<s iff s has high bit of m.
    int rank = 0;
    #define RANKSTEP(m, hb) { \
        float gj = SWZF(gs, m); \
        rank += (gj > gs || (gj == gs && (s & (hb)))) ? 1 : 0; }
    RANKSTEP(1, 1) RANKSTEP(2, 2) RANKSTEP(3, 2)
    RANKSTEP(4, 4) RANKSTEP(5, 4) RANKSTEP(6, 4) RANKSTEP(7, 4)
    #undef RANKSTEP
    const bool selected = rank < 4;

    #pragma unroll
    for (int c = 0; c < 8; ++c) {
        #pragma unroll
        for (int k = 0; k < 4; ++k)
            v[c][k] = selected ? v[c][k] : NEGINF;
    }

    // ---- sort each chunk of 4 descending (ties -> lower idx first) ----
    #pragma unroll
    for (int c = 0; c < 8; ++c) {
        #define CE(a,b) { \
            bool sw = (v[c][a] < v[c][b]) || (v[c][a] == v[c][b] && ix[c][a] > ix[c][b]); \
            float tv = sw ? v[c][b] : v[c][a]; \
            float uv = sw ? v[c][a] : v[c][b]; \
            int   ti = sw ? ix[c][b] : ix[c][a]; \
            int   ui = sw ? ix[c][a] : ix[c][b]; \
            v[c][a] = tv; v[c][b] = uv; ix[c][a] = ti; ix[c][b] = ui; }
        CE(0,1) CE(2,3) CE(0,2) CE(1,3) CE(1,2)
        #undef CE
    }

    // ---- 8 rounds: global argmax over 64 stream heads, advance winner ----
    float keepV = 0.0f; int keepI = 0;
    const int sbase8 = s << 3;
    #pragma unroll
    for (int r = 0; r < 8; ++r) {
        // depth-3 tournament over 8 chunk heads; strict > with left (lower
        // chunk = lower index) preferred on ties -> lowest-index-first.
        #define PICK(av, ai, bv, bi, rv, ri) { \
            bool t = ((bv) > (av)); \
            rv = t ? (bv) : (av); ri = t ? (bi) : (ai); }
        float w0v, w1v, w2v, w3v, x0v, x1v, bv;
        int   w0i, w1i, w2i, w3i, x0i, x1i, bi;
        PICK(v[0][0], ix[0][0], v[1][0], ix[1][0], w0v, w0i)
        PICK(v[2][0], ix[2][0], v[3][0], ix[3][0], w1v, w1i)
        PICK(v[4][0], ix[4][0], v[5][0], ix[5][0], w2v, w2i)
        PICK(v[6][0], ix[6][0], v[7][0], ix[7][0], w3v, w3i)
        PICK(w0v, w0i, w1v, w1i, x0v, x0i)
        PICK(w2v, w2i, w3v, w3i, x1v, x1i)
        PICK(x0v, x0i, x1v, x1i, bv, bi)
        #undef PICK
        // 8-lane butterfly argmax; index tie-break for cross-lane consistency
        #define BFLY(m) { \
            float ov = SWZF(bv, m); int oi = SWZI(bi, m); \
            bool t = (ov > bv) || (ov == bv && oi < bi); \
            bv = t ? ov : bv; bi = t ? oi : bi; }
        BFLY(1) BFLY(2) BFLY(4)
        #undef BFLY
        if (s == r) { keepV = bv; keepI = bi; }
        const int d = (bi >> 2) - sbase8;   // my chunk index if winner is mine
        #pragma unroll
        for (int c = 0; c < 8; ++c) {
            bool hit = (d == c);
            v[c][0]  = hit ? v[c][1]  : v[c][0];
            ix[c][0] = hit ? ix[c][1] : ix[c][0];
            v[c][1]  = hit ? v[c][2]  : v[c][1];
            ix[c][1] = hit ? ix[c][2] : ix[c][1];
            v[c][2]  = hit ? v[c][3]  : v[c][2];
            ix[c][2] = hit ? ix[c][3] : ix[c][2];
            v[c][3]  = hit ? NEGINF   : v[c][3];
        }
    }

    // ---- recover sigmoid score, renormalize, scale, store (coalesced) ----
    float w = keepV - bias[keepI];
    float sum = w;
    sum += SWZF(sum, 1);
    sum += SWZF(sum, 2);
    sum += SWZF(sum, 4);
    w = w / (sum + 1e-20f) * 2.5f;

    out_w[(size_t)token * 8 + s]  = w;
    out_id[(size_t)token * 8 + s] = (float)keepI;
}

extern "C" void kernel_launch(void* const* d_in, const int* in_sizes, int n_in,
                              void* d_out, int out_size, void* d_ws, size_t ws_size,
                              hipStream_t stream) {
    const float* logits = (const float*)d_in[0];
    const float* bias   = (const float*)d_in[1];
    const int E = in_sizes[1];          // 256
    const int T = in_sizes[0] / E;      // 131072
    float* out_w  = (float*)d_out;
    float* out_id = out_w + (size_t)T * 8;
    const int blocks = (T + 31) / 32;
    router_topk_kernel<<<blocks, 256, 0, stream>>>(logits, bias, out_w, out_id, T);
}